// Round 2
// baseline (743.392 us; speedup 1.0000x reference)
//
#include <hip/hip_runtime.h>
#include <math.h>

// DynamicRouting: C=1024 capsule groups, K=64 input capsules, H=512.
// Key identity: x_hat never needs materializing.
//   c_hat[c] = W @ (sum_k d[c,k] * enc[c,k,:])     (e_d then matvec)
//   b[c,k]  += enc[c,k,:] . (W^T @ c[c])           (matvec u then dots)
// One block per capsule c; enc[c] (128 KB) LDS-resident across all 3 iters.

#define K_CAPS 64
#define H_DIM 512
#define ENC_STRIDE 520   // 512 + 8 pad floats; %4==0 (float4-aligned), breaks bank alignment
#define NTHREADS 256

__launch_bounds__(NTHREADS, 1)
__global__ void routing_kernel(const float* __restrict__ enc,
                               const float* __restrict__ W,
                               float* __restrict__ out) {
    __shared__ float enc_s[K_CAPS * ENC_STRIDE];  // 133,120 B
    __shared__ float ed[H_DIM];     // e_d (iter weighted sum), 2 KB
    __shared__ float chat[H_DIM];   // pre-squash
    __shared__ float cvec[H_DIM];   // squashed output capsule
    __shared__ float uvec[H_DIM];   // W^T c
    __shared__ float bvec[K_CAPS];
    __shared__ float dvec[K_CAPS];
    __shared__ float red[4];
    __shared__ float s_scale;

    const int tid  = threadIdx.x;
    const int lane = tid & 63;
    const int wave = tid >> 6;
    const int c    = blockIdx.x;

    // ---- Stage enc[c] (64 x 512 fp32) into LDS, float4, padded rows ----
    {
        const float4* src = reinterpret_cast<const float4*>(enc + (size_t)c * K_CAPS * H_DIM);
        #pragma unroll 4
        for (int i = tid; i < K_CAPS * H_DIM / 4; i += NTHREADS) {
            float4 v = src[i];
            int k  = i >> 7;          // 128 float4 per row
            int h4 = (i & 127) << 2;  // float offset in row
            *reinterpret_cast<float4*>(&enc_s[k * ENC_STRIDE + h4]) = v;
        }
    }
    if (tid < K_CAPS) bvec[tid] = 0.0f;
    __syncthreads();

    for (int it = 0; it < 3; ++it) {
        // ---- d = softmax(b) over K=64 (wave 0 only) ----
        if (wave == 0) {
            float v = bvec[lane];
            float m = v;
            #pragma unroll
            for (int off = 32; off; off >>= 1) m = fmaxf(m, __shfl_xor(m, off));
            float e = expf(v - m);
            float s = e;
            #pragma unroll
            for (int off = 32; off; off >>= 1) s += __shfl_xor(s, off);
            dvec[lane] = e / s;
        }
        __syncthreads();

        // ---- e_d[h] = sum_k d[k] * enc[k][h]  (thread per h, 2 h's each) ----
        {
            float a0 = 0.f, a1 = 0.f;
            #pragma unroll 8
            for (int k = 0; k < K_CAPS; ++k) {
                float dk = dvec[k];
                a0 += dk * enc_s[k * ENC_STRIDE + tid];
                a1 += dk * enc_s[k * ENC_STRIDE + tid + 256];
            }
            ed[tid] = a0;
            ed[tid + 256] = a1;
        }
        __syncthreads();

        // ---- chat[g] = W[g,:] . e_d  (wave-per-row, float4, shuffle reduce) ----
        for (int g = wave; g < H_DIM; g += 4) {
            const float4* wr  = reinterpret_cast<const float4*>(W + (size_t)g * H_DIM);
            const float4* edv = reinterpret_cast<const float4*>(ed);
            float4 w0 = wr[lane];
            float4 w1 = wr[lane + 64];
            float4 e0 = edv[lane];
            float4 e1 = edv[lane + 64];
            float p = w0.x * e0.x + w0.y * e0.y + w0.z * e0.z + w0.w * e0.w
                    + w1.x * e1.x + w1.y * e1.y + w1.z * e1.z + w1.w * e1.w;
            #pragma unroll
            for (int off = 32; off; off >>= 1) p += __shfl_xor(p, off);
            if (lane == 0) chat[g] = p;
        }
        __syncthreads();

        // ---- squash: cvec = chat * norm/((1+norm)*sqrt(norm)) ----
        {
            float p = chat[tid] * chat[tid] + chat[tid + 256] * chat[tid + 256];
            #pragma unroll
            for (int off = 32; off; off >>= 1) p += __shfl_xor(p, off);
            if (lane == 0) red[wave] = p;
        }
        __syncthreads();
        if (tid == 0) {
            float norm = red[0] + red[1] + red[2] + red[3];
            s_scale = norm / ((1.0f + norm) * sqrtf(norm));
        }
        __syncthreads();
        {
            float s = s_scale;
            cvec[tid]       = chat[tid] * s;
            cvec[tid + 256] = chat[tid + 256] * s;
        }
        __syncthreads();

        if (it < 2) {
            // ---- u[h] = sum_g W[g][h] * cvec[g]  (thread per h, coalesced row reads) ----
            {
                float a0 = 0.f, a1 = 0.f;
                #pragma unroll 8
                for (int g = 0; g < H_DIM; ++g) {
                    float cg = cvec[g];
                    const float* wr = W + (size_t)g * H_DIM;
                    a0 += cg * wr[tid];
                    a1 += cg * wr[tid + 256];
                }
                uvec[tid] = a0;
                uvec[tid + 256] = a1;
            }
            __syncthreads();

            // ---- b[k] += enc[k,:] . u  (wave-per-row) ----
            for (int k = wave; k < K_CAPS; k += 4) {
                const float* er = &enc_s[k * ENC_STRIDE];
                const float4* uv = reinterpret_cast<const float4*>(uvec);
                float4 e0 = *reinterpret_cast<const float4*>(er + 4 * lane);
                float4 e1 = *reinterpret_cast<const float4*>(er + 4 * lane + 256);
                float4 u0 = uv[lane];
                float4 u1 = uv[lane + 64];
                float p = e0.x * u0.x + e0.y * u0.y + e0.z * u0.z + e0.w * u0.w
                        + e1.x * u1.x + e1.y * u1.y + e1.z * u1.z + e1.w * u1.w;
                #pragma unroll
                for (int off = 32; off; off >>= 1) p += __shfl_xor(p, off);
                if (lane == 0) bvec[k] += p;
            }
            __syncthreads();
        }
    }

    // ---- write final capsule ----
    out[(size_t)c * H_DIM + tid]       = cvec[tid];
    out[(size_t)c * H_DIM + tid + 256] = cvec[tid + 256];
}

extern "C" void kernel_launch(void* const* d_in, const int* in_sizes, int n_in,
                              void* d_out, int out_size, void* d_ws, size_t ws_size,
                              hipStream_t stream) {
    const float* enc = (const float*)d_in[0];  // [1024, 64, 512] fp32
    const float* W   = (const float*)d_in[1];  // [512, 512] fp32
    float* out       = (float*)d_out;          // [1024, 512] fp32
    (void)in_sizes; (void)n_in; (void)d_ws; (void)ws_size; (void)out_size;

    routing_kernel<<<1024, NTHREADS, 0, stream>>>(enc, W, out);
}

// Round 3
// 219.740 us; speedup vs baseline: 3.3831x; 3.3831x over previous
//
#include <hip/hip_runtime.h>
#include <math.h>

// DynamicRouting: C=1024, K=64, H=512.
// squash(t) = alpha * t  (scalar!), so with G = W^T W (precomputed once):
//   iter<2 :  e_d = Enc^T d ;  n2 = e_d^T (G e_d) ;  alpha = sqrt(n2)/(1+n2)
//             b_k += alpha * (Enc (G e_d))_k          <-- ONE G-stream per iter
//   iter==2:  chat = W e_d ;  n2 = ||chat||^2 ;  out = alpha * chat
// 3 big-matrix streams per capsule (2xG + 1xW) instead of 5xW.
// One block per capsule, enc (128 KB) LDS-resident, 1024 threads (16 waves)
// to hide L2 latency (round-2 counters: occupancy 12%, VALUBusy 8.9% -> latency-bound).

#define K_CAPS 64
#define H_DIM 512
#define ENC_STRIDE 520
#define NT 1024

// ---------------- G = W^T W  (512x512), tiled SGEMM, 8x8 blocks x 256 thr ----
__launch_bounds__(256)
__global__ void gram_kernel(const float* __restrict__ W, float* __restrict__ G) {
    __shared__ float As[64][68];
    __shared__ float Bs[64][68];
    const int i0 = blockIdx.x * 64;
    const int j0 = blockIdx.y * 64;
    const int tid = threadIdx.x;
    float acc[4][4] = {};

    for (int hc = 0; hc < H_DIM; hc += 64) {
        #pragma unroll
        for (int t = tid; t < 64 * 16; t += 256) {   // 1024 float4 per tile
            int r  = t >> 4;
            int c4 = (t & 15) << 2;
            float4 va = *reinterpret_cast<const float4*>(&W[(size_t)(hc + r) * H_DIM + i0 + c4]);
            float4 vb = *reinterpret_cast<const float4*>(&W[(size_t)(hc + r) * H_DIM + j0 + c4]);
            *reinterpret_cast<float4*>(&As[r][c4]) = va;
            *reinterpret_cast<float4*>(&Bs[r][c4]) = vb;
        }
        __syncthreads();
        const int ti = (tid >> 4) << 2;
        const int tj = (tid & 15) << 2;
        #pragma unroll 8
        for (int h = 0; h < 64; ++h) {
            float a0 = As[h][ti], a1 = As[h][ti + 1], a2 = As[h][ti + 2], a3 = As[h][ti + 3];
            float b0 = Bs[h][tj], b1 = Bs[h][tj + 1], b2 = Bs[h][tj + 2], b3 = Bs[h][tj + 3];
            acc[0][0] += a0 * b0; acc[0][1] += a0 * b1; acc[0][2] += a0 * b2; acc[0][3] += a0 * b3;
            acc[1][0] += a1 * b0; acc[1][1] += a1 * b1; acc[1][2] += a1 * b2; acc[1][3] += a1 * b3;
            acc[2][0] += a2 * b0; acc[2][1] += a2 * b1; acc[2][2] += a2 * b2; acc[2][3] += a2 * b3;
            acc[3][0] += a3 * b0; acc[3][1] += a3 * b1; acc[3][2] += a3 * b2; acc[3][3] += a3 * b3;
        }
        __syncthreads();
    }
    const int ti = (tid >> 4) << 2;
    const int tj = (tid & 15) << 2;
    #pragma unroll
    for (int a = 0; a < 4; ++a) {
        float4 v = make_float4(acc[a][0], acc[a][1], acc[a][2], acc[a][3]);
        *reinterpret_cast<float4*>(&G[(size_t)(i0 + ti + a) * H_DIM + j0 + tj]) = v;
    }
}

// ---------------- routing: one block per capsule ----------------------------
__launch_bounds__(NT, 1)
__global__ void routing_kernel(const float* __restrict__ enc,
                               const float* __restrict__ W,
                               const float* __restrict__ G,
                               float* __restrict__ out) {
    __shared__ float enc_s[K_CAPS * ENC_STRIDE];   // 133,120 B
    __shared__ float ed[H_DIM];
    __shared__ float ed2[2 * H_DIM];
    __shared__ float gv[H_DIM];                    // G*e_d (iters 0,1) or chat (iter 2)
    __shared__ float bvec[K_CAPS];
    __shared__ float dvec[K_CAPS];
    __shared__ float red[8];
    __shared__ float s_alpha;

    const int tid  = threadIdx.x;
    const int lane = tid & 63;
    const int wave = tid >> 6;       // 0..15
    const int c    = blockIdx.x;

    // ---- stage enc[c] (64x512 fp32) into LDS, float4 coalesced ----
    {
        const float4* src = reinterpret_cast<const float4*>(enc + (size_t)c * K_CAPS * H_DIM);
        #pragma unroll
        for (int i = 0; i < 8; ++i) {
            int idx = tid + i * NT;                // 8192 float4 total
            float4 v = src[idx];
            int k  = idx >> 7;
            int h4 = (idx & 127) << 2;
            *reinterpret_cast<float4*>(&enc_s[k * ENC_STRIDE + h4]) = v;
        }
    }
    if (tid < K_CAPS) bvec[tid] = 0.0f;
    __syncthreads();

    for (int it = 0; it < 3; ++it) {
        // ---- d = softmax(b), wave 0 ----
        if (wave == 0) {
            float v = bvec[lane];
            float m = v;
            #pragma unroll
            for (int off = 32; off; off >>= 1) m = fmaxf(m, __shfl_xor(m, off));
            float e = expf(v - m);
            float s = e;
            #pragma unroll
            for (int off = 32; off; off >>= 1) s += __shfl_xor(s, off);
            dvec[lane] = e / s;
        }
        __syncthreads();

        // ---- e_d[h] = sum_k d_k enc[k][h], split k across 2 halves ----
        {
            const int h    = tid & 511;
            const int half = tid >> 9;
            const float* base = &enc_s[half * 32 * ENC_STRIDE + h];
            float a = 0.f;
            #pragma unroll 8
            for (int k = 0; k < 32; ++k) a += dvec[half * 32 + k] * base[k * ENC_STRIDE];
            ed2[half * H_DIM + h] = a;
        }
        __syncthreads();
        if (tid < H_DIM) ed[tid] = ed2[tid] + ed2[H_DIM + tid];
        __syncthreads();

        // ---- gv = M * ed   (M = G for iters 0,1; M = W for iter 2) ----
        {
            const float* M = (it < 2) ? G : W;
            const float4* edv = reinterpret_cast<const float4*>(ed);
            const float4  e0  = edv[lane * 2];
            const float4  e1  = edv[lane * 2 + 1];
            #pragma unroll 2
            for (int r0 = wave * 32; r0 < wave * 32 + 32; r0 += 2) {
                const float4* row0 = reinterpret_cast<const float4*>(&M[(size_t)r0 * H_DIM]);
                const float4* row1 = reinterpret_cast<const float4*>(&M[(size_t)(r0 + 1) * H_DIM]);
                float4 w00 = row0[lane * 2], w01 = row0[lane * 2 + 1];
                float4 w10 = row1[lane * 2], w11 = row1[lane * 2 + 1];
                float p0 = w00.x * e0.x + w00.y * e0.y + w00.z * e0.z + w00.w * e0.w
                         + w01.x * e1.x + w01.y * e1.y + w01.z * e1.z + w01.w * e1.w;
                float p1 = w10.x * e0.x + w10.y * e0.y + w10.z * e0.z + w10.w * e0.w
                         + w11.x * e1.x + w11.y * e1.y + w11.z * e1.z + w11.w * e1.w;
                #pragma unroll
                for (int off = 32; off; off >>= 1) {
                    p0 += __shfl_xor(p0, off);
                    p1 += __shfl_xor(p1, off);
                }
                if (lane == 0) { gv[r0] = p0; gv[r0 + 1] = p1; }
            }
        }
        __syncthreads();

        // ---- n2 = ed.gv (iters 0,1: = ||W ed||^2)  or  ||chat||^2 (iter 2) ----
        if (tid < H_DIM) {
            float p = (it < 2) ? ed[tid] * gv[tid] : gv[tid] * gv[tid];
            #pragma unroll
            for (int off = 32; off; off >>= 1) p += __shfl_xor(p, off);
            if (lane == 0) red[wave] = p;
        }
        __syncthreads();
        if (tid == 0) {
            float n2 = 0.f;
            #pragma unroll
            for (int w = 0; w < 8; ++w) n2 += red[w];
            s_alpha = sqrtf(n2) / (1.0f + n2);
        }
        __syncthreads();

        if (it < 2) {
            // ---- b_k += alpha * enc_k . (G e_d) ----
            const float alpha = s_alpha;
            const float4* gvv = reinterpret_cast<const float4*>(gv);
            const float4  g0  = gvv[lane * 2];
            const float4  g1  = gvv[lane * 2 + 1];
            for (int k = wave; k < K_CAPS; k += 16) {
                const float4* er = reinterpret_cast<const float4*>(&enc_s[k * ENC_STRIDE]);
                float4 x0 = er[lane * 2], x1 = er[lane * 2 + 1];
                float p = x0.x * g0.x + x0.y * g0.y + x0.z * g0.z + x0.w * g0.w
                        + x1.x * g1.x + x1.y * g1.y + x1.z * g1.z + x1.w * g1.w;
                #pragma unroll
                for (int off = 32; off; off >>= 1) p += __shfl_xor(p, off);
                if (lane == 0) bvec[k] += alpha * p;
            }
            __syncthreads();
        } else {
            // ---- out = alpha * chat ----
            if (tid < H_DIM) out[(size_t)c * H_DIM + tid] = s_alpha * gv[tid];
        }
    }
}

extern "C" void kernel_launch(void* const* d_in, const int* in_sizes, int n_in,
                              void* d_out, int out_size, void* d_ws, size_t ws_size,
                              hipStream_t stream) {
    const float* enc = (const float*)d_in[0];  // [1024, 64, 512] fp32
    const float* W   = (const float*)d_in[1];  // [512, 512] fp32
    float* out       = (float*)d_out;          // [1024, 512] fp32
    float* G         = (float*)d_ws;           // 512*512 fp32 = 1 MB scratch
    (void)in_sizes; (void)n_in; (void)ws_size; (void)out_size;

    gram_kernel<<<dim3(8, 8), 256, 0, stream>>>(W, G);
    routing_kernel<<<1024, NT, 0, stream>>>(enc, W, G, out);
}

// Round 4
// 200.754 us; speedup vs baseline: 3.7030x; 1.0946x over previous
//
#include <hip/hip_runtime.h>
#include <math.h>

// DynamicRouting: C=1024, K=64, H=512.
// squash(t) = alpha*t (scalar), G = W^T W (symmetric, precomputed):
//   iter<2 :  gv = G ed ; n2 = ed.gv ; alpha = sqrt(n2)/(1+n2) ; b_k += alpha*(enc_k.gv)
//   iter==2:  chat = W ed (via WT, columns coalesced) ; out = alpha*chat
// All matvecs: thread-per-output-column, ed broadcast from LDS, no shuffles.
// Iter 0: d == 1/64 exactly (b=0), ed computed during staging.

#define K_CAPS 64
#define H_DIM 512
#define ENC_STRIDE 520
#define NT 1024

// ---------------- G = W^T W  (512x512) ----------------
__launch_bounds__(256)
__global__ void gram_kernel(const float* __restrict__ W, float* __restrict__ G) {
    __shared__ float As[64][68];
    __shared__ float Bs[64][68];
    const int i0 = blockIdx.x * 64;
    const int j0 = blockIdx.y * 64;
    const int tid = threadIdx.x;
    float acc[4][4] = {};

    for (int hc = 0; hc < H_DIM; hc += 64) {
        #pragma unroll
        for (int t = tid; t < 64 * 16; t += 256) {
            int r  = t >> 4;
            int c4 = (t & 15) << 2;
            float4 va = *reinterpret_cast<const float4*>(&W[(size_t)(hc + r) * H_DIM + i0 + c4]);
            float4 vb = *reinterpret_cast<const float4*>(&W[(size_t)(hc + r) * H_DIM + j0 + c4]);
            *reinterpret_cast<float4*>(&As[r][c4]) = va;
            *reinterpret_cast<float4*>(&Bs[r][c4]) = vb;
        }
        __syncthreads();
        const int ti = (tid >> 4) << 2;
        const int tj = (tid & 15) << 2;
        #pragma unroll 8
        for (int h = 0; h < 64; ++h) {
            float a0 = As[h][ti], a1 = As[h][ti + 1], a2 = As[h][ti + 2], a3 = As[h][ti + 3];
            float b0 = Bs[h][tj], b1 = Bs[h][tj + 1], b2 = Bs[h][tj + 2], b3 = Bs[h][tj + 3];
            acc[0][0] += a0 * b0; acc[0][1] += a0 * b1; acc[0][2] += a0 * b2; acc[0][3] += a0 * b3;
            acc[1][0] += a1 * b0; acc[1][1] += a1 * b1; acc[1][2] += a1 * b2; acc[1][3] += a1 * b3;
            acc[2][0] += a2 * b0; acc[2][1] += a2 * b1; acc[2][2] += a2 * b2; acc[2][3] += a2 * b3;
            acc[3][0] += a3 * b0; acc[3][1] += a3 * b1; acc[3][2] += a3 * b2; acc[3][3] += a3 * b3;
        }
        __syncthreads();
    }
    const int ti = (tid >> 4) << 2;
    const int tj = (tid & 15) << 2;
    #pragma unroll
    for (int a = 0; a < 4; ++a) {
        float4 v = make_float4(acc[a][0], acc[a][1], acc[a][2], acc[a][3]);
        *reinterpret_cast<float4*>(&G[(size_t)(i0 + ti + a) * H_DIM + j0 + tj]) = v;
    }
}

// ---------------- WT = W^T ----------------
__launch_bounds__(256)
__global__ void transpose_kernel(const float* __restrict__ W, float* __restrict__ WT) {
    __shared__ float t[64][65];
    const int r0 = blockIdx.y << 6, c0 = blockIdx.x << 6;
    for (int i = threadIdx.x; i < 4096; i += 256) {
        int r = i >> 6, c = i & 63;
        t[r][c] = W[(size_t)(r0 + r) * H_DIM + c0 + c];
    }
    __syncthreads();
    for (int i = threadIdx.x; i < 4096; i += 256) {
        int r = i >> 6, c = i & 63;
        WT[(size_t)(c0 + r) * H_DIM + r0 + c] = t[c][r];
    }
}

// ---------------- routing: one block per capsule ----------------
__launch_bounds__(NT, 1)
__global__ void routing_kernel(const float* __restrict__ enc,
                               const float* __restrict__ W,
                               const float* __restrict__ G,
                               const float* __restrict__ WT,
                               float* __restrict__ out,
                               int use_wt) {
    __shared__ float enc_s[K_CAPS * ENC_STRIDE];   // 133,120 B
    __shared__ float scratch[4096];                // 16 KB: ed2 halves / matvec psums
    __shared__ float ed[H_DIM];
    __shared__ float gv[H_DIM];
    __shared__ float bvec[K_CAPS];
    __shared__ float dvec[K_CAPS];
    __shared__ float red[8];
    __shared__ float s_alpha;

    const int tid  = threadIdx.x;
    const int lane = tid & 63;
    const int wave = tid >> 6;       // 0..15
    const int c    = blockIdx.x;

    // ---- stage enc[c] into LDS; fuse iter-0 e_d (d == 1/64) ----
    {
        const float4* src = reinterpret_cast<const float4*>(enc + (size_t)c * K_CAPS * H_DIM);
        float4 acc = make_float4(0.f, 0.f, 0.f, 0.f);
        #pragma unroll
        for (int i = 0; i < 8; ++i) {
            int idx = tid + (i << 10);
            float4 v = src[idx];
            int k  = idx >> 7;
            int h4 = (idx & 127) << 2;
            *reinterpret_cast<float4*>(&enc_s[k * ENC_STRIDE + h4]) = v;
            acc.x += v.x; acc.y += v.y; acc.z += v.z; acc.w += v.w;
        }
        *reinterpret_cast<float4*>(&scratch[((tid >> 7) << 9) + ((tid & 127) << 2)]) = acc;
    }
    if (tid < K_CAPS) bvec[tid] = 0.0f;
    __syncthreads();
    if (tid < H_DIM) {
        float s = 0.f;
        #pragma unroll
        for (int sl = 0; sl < 8; ++sl) s += scratch[(sl << 9) + tid];
        ed[tid] = s * (1.0f / 64.0f);
    }
    __syncthreads();

    for (int it = 0; it < 3; ++it) {
        if (it > 0) {
            // ---- d = softmax(b), wave 0 ----
            if (wave == 0) {
                float v = bvec[lane];
                float m = v;
                #pragma unroll
                for (int off = 32; off; off >>= 1) m = fmaxf(m, __shfl_xor(m, off));
                float e = expf(v - m);
                float s = e;
                #pragma unroll
                for (int off = 32; off; off >>= 1) s += __shfl_xor(s, off);
                dvec[lane] = e / s;
            }
            __syncthreads();

            // ---- e_d[h] = sum_k d_k enc[k][h] (2 halves) ----
            {
                const int h    = tid & 511;
                const int half = tid >> 9;
                const float* base = &enc_s[half * 32 * ENC_STRIDE + h];
                float a = 0.f;
                #pragma unroll 8
                for (int k = 0; k < 32; ++k) a += dvec[half * 32 + k] * base[k * ENC_STRIDE];
                scratch[half * H_DIM + h] = a;
            }
            __syncthreads();
            if (tid < H_DIM) ed[tid] = scratch[tid] + scratch[H_DIM + tid];
            __syncthreads();
        }

        // ---- gv[j] = sum_h ed[h] * M[h][j]  (thread-per-column, no shuffles)
        //      M = G (symmetric => G ed) for it<2 ; M = WT (=> W ed) for it==2
        const int wt_path = (it == 2) && use_wt;
        if (it < 2 || wt_path) {
            const float* M = (it < 2) ? G : WT;
            const int c4 = (tid & 127) << 2;
            const int sl = tid >> 7;          // 0..7, uniform per wave
            const float* Mb = M + (size_t)(sl << 6) * H_DIM + c4;
            float4 a = make_float4(0.f, 0.f, 0.f, 0.f);
            #pragma unroll 8
            for (int h = 0; h < 64; ++h) {
                float e = ed[(sl << 6) + h];
                float4 m = *reinterpret_cast<const float4*>(Mb + (size_t)h * H_DIM);
                a.x += e * m.x; a.y += e * m.y; a.z += e * m.z; a.w += e * m.w;
            }
            *reinterpret_cast<float4*>(&scratch[(sl << 9) + c4]) = a;
            __syncthreads();
            if (tid < H_DIM) {
                float s = 0.f;
                #pragma unroll
                for (int sl2 = 0; sl2 < 8; ++sl2) s += scratch[(sl2 << 9) + tid];
                gv[tid] = s;
            }
            __syncthreads();
        } else {
            // fallback: chat = W ed, wave-per-2-rows with shuffle reduce
            const float4* edv = reinterpret_cast<const float4*>(ed);
            const float4  e0  = edv[lane * 2];
            const float4  e1  = edv[lane * 2 + 1];
            #pragma unroll 2
            for (int r0 = wave * 32; r0 < wave * 32 + 32; r0 += 2) {
                const float4* row0 = reinterpret_cast<const float4*>(&W[(size_t)r0 * H_DIM]);
                const float4* row1 = reinterpret_cast<const float4*>(&W[(size_t)(r0 + 1) * H_DIM]);
                float4 w00 = row0[lane * 2], w01 = row0[lane * 2 + 1];
                float4 w10 = row1[lane * 2], w11 = row1[lane * 2 + 1];
                float p0 = w00.x * e0.x + w00.y * e0.y + w00.z * e0.z + w00.w * e0.w
                         + w01.x * e1.x + w01.y * e1.y + w01.z * e1.z + w01.w * e1.w;
                float p1 = w10.x * e0.x + w10.y * e0.y + w10.z * e0.z + w10.w * e0.w
                         + w11.x * e1.x + w11.y * e1.y + w11.z * e1.z + w11.w * e1.w;
                #pragma unroll
                for (int off = 32; off; off >>= 1) {
                    p0 += __shfl_xor(p0, off);
                    p1 += __shfl_xor(p1, off);
                }
                if (lane == 0) { gv[r0] = p0; gv[r0 + 1] = p1; }
            }
            __syncthreads();
        }

        // ---- n2 ----
        if (tid < H_DIM) {
            float p = (it < 2) ? ed[tid] * gv[tid] : gv[tid] * gv[tid];
            #pragma unroll
            for (int off = 32; off; off >>= 1) p += __shfl_xor(p, off);
            if (lane == 0) red[wave] = p;
        }
        __syncthreads();
        if (tid == 0) {
            float n2 = red[0] + red[1] + red[2] + red[3] + red[4] + red[5] + red[6] + red[7];
            s_alpha = sqrtf(n2) / (1.0f + n2);
        }
        __syncthreads();

        if (it < 2) {
            // ---- b_k += alpha * enc_k . gv  (stride-1 lane reads, conflict-free) ----
            const float alpha = s_alpha;
            float gr[8];
            #pragma unroll
            for (int i = 0; i < 8; ++i) gr[i] = gv[(i << 6) + lane];
            for (int k = wave; k < K_CAPS; k += 16) {
                const float* er = &enc_s[k * ENC_STRIDE];
                float p = 0.f;
                #pragma unroll
                for (int i = 0; i < 8; ++i) p += er[(i << 6) + lane] * gr[i];
                #pragma unroll
                for (int off = 32; off; off >>= 1) p += __shfl_xor(p, off);
                if (lane == 0) bvec[k] += alpha * p;
            }
            __syncthreads();
        } else {
            if (tid < H_DIM) out[(size_t)c * H_DIM + tid] = s_alpha * gv[tid];
        }
    }
}

extern "C" void kernel_launch(void* const* d_in, const int* in_sizes, int n_in,
                              void* d_out, int out_size, void* d_ws, size_t ws_size,
                              hipStream_t stream) {
    const float* enc = (const float*)d_in[0];  // [1024, 64, 512] fp32
    const float* W   = (const float*)d_in[1];  // [512, 512] fp32
    float* out       = (float*)d_out;          // [1024, 512] fp32
    float* G         = (float*)d_ws;           // 1 MB
    const int use_wt = (ws_size >= (2u << 20)) ? 1 : 0;
    float* WT        = use_wt ? (G + H_DIM * H_DIM) : G;  // +1 MB if available
    (void)in_sizes; (void)n_in; (void)out_size;

    gram_kernel<<<dim3(8, 8), 256, 0, stream>>>(W, G);
    if (use_wt) transpose_kernel<<<dim3(8, 8), 256, 0, stream>>>(W, WT);
    routing_kernel<<<1024, NT, 0, stream>>>(enc, W, G, WT, out, use_wt);
}

// Round 7
// 124.280 us; speedup vs baseline: 5.9816x; 1.6153x over previous
//
#include <hip/hip_runtime.h>
#include <math.h>

// DynamicRouting: C=1024, K=64, H=512.
// Round-5 structure: per capsule block, compute x_hat_c = Enc_c @ W^T (64x512)
// with fp16 MFMA into 64KB LDS, then run all 3 routing iterations as pure
// LDS passes (no G/W streaming per iteration -- round 2-4 bottleneck).
//   c_hat = sum_k d_k x_hat_k ; alpha = sqrt(n2)/(1+n2), n2=||c_hat||^2
//   b_k  += alpha * (x_hat_k . c_hat) ; out = alpha * c_hat (iter 2)
// fp16 error budget: x_hat rel ~5e-4 -> output absmax ~1e-3 << 4.08e-3 thr.

#define KC 64
#define HD 512
#define NT 512

typedef _Float16 half8  __attribute__((ext_vector_type(8)));
typedef _Float16 half4v __attribute__((ext_vector_type(4)));
typedef float    f32x4  __attribute__((ext_vector_type(4)));

// ---------------- W -> fp16 ----------------
__launch_bounds__(256)
__global__ void cast_w_kernel(const float* __restrict__ W, _Float16* __restrict__ W16) {
    int i = blockIdx.x * 256 + threadIdx.x;       // 65536 float4 total
    float4 v = reinterpret_cast<const float4*>(W)[i];
    half4v h = { (_Float16)v.x, (_Float16)v.y, (_Float16)v.z, (_Float16)v.w };
    reinterpret_cast<half4v*>(W16)[i] = h;
}

// ---------------- fused proj + routing, one block per capsule ----------------
__launch_bounds__(NT, 1)
__global__ void routing_kernel(const float* __restrict__ enc,
                               const _Float16* __restrict__ W16,
                               float* __restrict__ out) {
    __shared__ _Float16 xh[KC][HD];        // 64 KB  x_hat fp16
    __shared__ _Float16 slab[2][KC][72];   // 18.4 KB enc fp16 k-slabs (dbuf, +8 pad)
    __shared__ float chat[HD];
    __shared__ float scr[2][HD];
    __shared__ float bvec[KC];
    __shared__ float dvec[KC];
    __shared__ float red[8];
    __shared__ float s_alpha;

    const int tid  = threadIdx.x;
    const int lane = tid & 63;
    const int wave = tid >> 6;             // 0..7  (wave-grid 1x8 over g)
    const int c    = blockIdx.x;
    const size_t ebase = (size_t)c * (KC * HD);

    if (tid < KC) { bvec[tid] = 0.0f; dvec[tid] = 1.0f / 64.0f; }

    // ---- stage enc slab hs (64 k x 64 h fp32 -> fp16), coalesced float4 ----
    auto stage = [&](int hs, int b) {
        #pragma unroll
        for (int j = 0; j < 2; ++j) {
            int idx = tid + (j << 9);              // 0..1023 float4s
            int r   = idx >> 4;
            int c4  = (idx & 15) << 2;
            float4 v = *reinterpret_cast<const float4*>(enc + ebase + (size_t)r * HD + hs * 64 + c4);
            half4v h = { (_Float16)v.x, (_Float16)v.y, (_Float16)v.z, (_Float16)v.w };
            *reinterpret_cast<half4v*>(&slab[b][r][c4]) = h;
        }
    };

    // ---- projection: xh = Enc_c @ W^T, fp16 MFMA 16x16x32 ----
    f32x4 acc[16];
    #pragma unroll
    for (int i = 0; i < 16; ++i) acc[i] = (f32x4){0.f, 0.f, 0.f, 0.f};

    const int l15 = lane & 15, l4 = lane >> 4;
    // B-frag base: lane holds W16[g0 + (l&15)][(l>>4)*8 .. +7]  (BT-GEMM form)
    const _Float16* wb = W16 + (size_t)(wave * 64 + l15) * HD + l4 * 8;

    stage(0, 0);
    for (int hs = 0; hs < 8; ++hs) {
        __syncthreads();                            // slab[hs&1] ready; prior reads of other buf done
        if (hs < 7) stage(hs + 1, (hs + 1) & 1);
        const int b = hs & 1;
        #pragma unroll
        for (int ks = 0; ks < 2; ++ks) {
            half8 af[4], bf[4];
            #pragma unroll
            for (int i = 0; i < 4; ++i)
                af[i] = *reinterpret_cast<const half8*>(&slab[b][l15 + 16 * i][ks * 32 + l4 * 8]);
            #pragma unroll
            for (int j = 0; j < 4; ++j)
                bf[j] = *reinterpret_cast<const half8*>(wb + j * (16 * HD) + hs * 64 + ks * 32);
            #pragma unroll
            for (int i = 0; i < 4; ++i) {
                #pragma unroll
                for (int j = 0; j < 4; ++j)
                    acc[i * 4 + j] = __builtin_amdgcn_mfma_f32_16x16x32_f16(af[i], bf[j], acc[i * 4 + j], 0, 0, 0);
            }
        }
    }
    // epilogue: acc -> xh fp16.  C/D layout: col=lane&15 (g), row=(lane>>4)*4+reg (k)
    #pragma unroll
    for (int i = 0; i < 4; ++i) {
        #pragma unroll
        for (int j = 0; j < 4; ++j) {
            f32x4 v = acc[i * 4 + j];
            int g  = wave * 64 + j * 16 + l15;
            int rb = i * 16 + l4 * 4;
            #pragma unroll
            for (int r = 0; r < 4; ++r) xh[rb + r][g] = (_Float16)v[r];
        }
    }
    __syncthreads();

    // ---- routing: 3 iterations, all LDS ----
    for (int it = 0; it < 3; ++it) {
        if (it > 0) {
            if (wave == 0) {                        // softmax over K=64
                float v = bvec[lane];
                float m = v;
                #pragma unroll
                for (int off = 32; off; off >>= 1) m = fmaxf(m, __shfl_xor(m, off));
                float e = expf(v - m);
                float s = e;
                #pragma unroll
                for (int off = 32; off; off >>= 1) s += __shfl_xor(s, off);
                dvec[lane] = e / s;
            }
            __syncthreads();
        }

        // chat-pass: thread (kh = tid>>8, hp = tid&255) covers 2 h's over 32 k's
        {
            const int kh = tid >> 8, hp = tid & 255;
            float c0 = 0.f, c1 = 0.f;
            #pragma unroll 8
            for (int k = 0; k < 32; ++k) {
                int kk = kh * 32 + k;
                float dk = dvec[kk];
                c0 += dk * (float)xh[kk][2 * hp];
                c1 += dk * (float)xh[kk][2 * hp + 1];
            }
            scr[kh][2 * hp]     = c0;
            scr[kh][2 * hp + 1] = c1;
        }
        __syncthreads();
        {
            float cv = scr[0][tid] + scr[1][tid];
            chat[tid] = cv;
            float p = cv * cv;
            #pragma unroll
            for (int off = 32; off; off >>= 1) p += __shfl_xor(p, off);
            if (lane == 0) red[wave] = p;
        }
        __syncthreads();
        if (tid == 0) {
            float n2 = red[0] + red[1] + red[2] + red[3] + red[4] + red[5] + red[6] + red[7];
            s_alpha = sqrtf(n2) / (1.0f + n2);
        }
        __syncthreads();

        if (it < 2) {
            // b_k += alpha * (xh_k . chat) : wave per k-row, b128 fp16 reads
            float4 cA = *reinterpret_cast<const float4*>(&chat[lane * 8]);
            float4 cB = *reinterpret_cast<const float4*>(&chat[lane * 8 + 4]);
            const float alpha = s_alpha;
            #pragma unroll
            for (int kk = 0; kk < 8; ++kk) {
                int k = wave * 8 + kk;
                half8 x = *reinterpret_cast<const half8*>(&xh[k][lane * 8]);
                float p = (float)x[0] * cA.x + (float)x[1] * cA.y + (float)x[2] * cA.z + (float)x[3] * cA.w
                        + (float)x[4] * cB.x + (float)x[5] * cB.y + (float)x[6] * cB.z + (float)x[7] * cB.w;
                #pragma unroll
                for (int off = 32; off; off >>= 1) p += __shfl_xor(p, off);
                if (lane == 0) bvec[k] += alpha * p;
            }
            __syncthreads();
        } else {
            out[(size_t)c * HD + tid] = s_alpha * chat[tid];
        }
    }
}

extern "C" void kernel_launch(void* const* d_in, const int* in_sizes, int n_in,
                              void* d_out, int out_size, void* d_ws, size_t ws_size,
                              hipStream_t stream) {
    const float* enc = (const float*)d_in[0];   // [1024, 64, 512] fp32
    const float* W   = (const float*)d_in[1];   // [512, 512] fp32
    float* out       = (float*)d_out;           // [1024, 512] fp32
    _Float16* W16    = (_Float16*)d_ws;         // 512 KB (ws >= 2 MB confirmed round 4)
    (void)in_sizes; (void)n_in; (void)ws_size; (void)out_size;

    cast_w_kernel<<<256, 256, 0, stream>>>(W, W16);
    routing_kernel<<<1024, NT, 0, stream>>>(enc, W16, out);
}

// Round 8
// 92.069 us; speedup vs baseline: 8.0743x; 1.3499x over previous
//
#include <hip/hip_runtime.h>
#include <math.h>

// DynamicRouting: C=1024, K=64, H=512.
// Round-8: x_hat stays in MFMA accumulator REGISTERS (never LDS).
// Wave layout (verified by round-7 pass): acc[cap][i*4+j][r] holds
//   xh[k][g] with k = i*16 + (lane>>4)*4 + r, g = wave*64 + j*16 + (lane&15).
// Routing per iter: chat via reg-FMA + xor16/32 (l4-reduce);
//   n2 via xor1..8; b-update via reg-dot + xor1..8 (l15-reduce) + 8-wave LDS combine.
// 2 capsules/block: B-frags (W16) loaded once, used for both -> halves W16/L1
// traffic and halves capsule-chain rounds per CU (round-7 was latency-bound:
// MfmaUtil 9.5 / VALU 11 / HBM 6.7%, 3.28M LDS bank conflicts from xh writes).

#define KC 64
#define HD 512
#define NT 512
#define CPB 2

typedef _Float16 half8  __attribute__((ext_vector_type(8)));
typedef _Float16 half4v __attribute__((ext_vector_type(4)));
typedef float    f32x4  __attribute__((ext_vector_type(4)));

// ---------------- W -> fp16 ----------------
__launch_bounds__(256)
__global__ void cast_w_kernel(const float* __restrict__ W, _Float16* __restrict__ W16) {
    int i = blockIdx.x * 256 + threadIdx.x;       // 65536 float4 total
    float4 v = reinterpret_cast<const float4*>(W)[i];
    half4v h = { (_Float16)v.x, (_Float16)v.y, (_Float16)v.z, (_Float16)v.w };
    reinterpret_cast<half4v*>(W16)[i] = h;
}

// ---------------- fused proj + routing, 2 capsules per block ----------------
__launch_bounds__(NT, 1)
__global__ void routing_kernel(const float* __restrict__ enc,
                               const _Float16* __restrict__ W16,
                               float* __restrict__ out) {
    __shared__ _Float16 slab[2][CPB][KC][72];   // 36.9 KB enc fp16 (dbuf, +8 pad)
    __shared__ float chatL[CPB][HD];            // 4 KB
    __shared__ float bvec[CPB][KC];
    __shared__ float dvec[CPB][KC];
    __shared__ float bpart[8][CPB][KC];         // 4 KB per-wave b partials
    __shared__ float red[8][CPB];
    __shared__ float s_alpha[CPB];

    const int tid  = threadIdx.x;
    const int lane = tid & 63;
    const int wave = tid >> 6;                  // 0..7 (g-slice owner)
    const int l15  = lane & 15, l4 = lane >> 4;
    const int c0   = blockIdx.x * CPB;

    if (tid < CPB * KC) bvec[tid >> 6][tid & 63] = 0.0f;

    f32x4 acc[CPB][16];
    #pragma unroll
    for (int cap = 0; cap < CPB; ++cap)
        #pragma unroll
        for (int i = 0; i < 16; ++i) acc[cap][i] = (f32x4){0.f, 0.f, 0.f, 0.f};

    // ---- stage enc slab hs for both capsules (64k x 64h fp32 -> fp16) ----
    auto stage = [&](int hs, int b) {
        #pragma unroll
        for (int cap = 0; cap < CPB; ++cap) {
            const float* ebase = enc + (size_t)(c0 + cap) * (KC * HD);
            #pragma unroll
            for (int j = 0; j < 2; ++j) {
                int idx = tid + (j << 9);              // 1024 float4 per cap
                int r   = idx >> 4;
                int c4  = (idx & 15) << 2;
                float4 v = *reinterpret_cast<const float4*>(ebase + (size_t)r * HD + hs * 64 + c4);
                half4v h = { (_Float16)v.x, (_Float16)v.y, (_Float16)v.z, (_Float16)v.w };
                *reinterpret_cast<half4v*>(&slab[b][cap][r][c4]) = h;
            }
        }
    };

    const _Float16* wb = W16 + (size_t)(wave * 64 + l15) * HD + l4 * 8;

    // ---- projection: acc = Enc_c @ W^T, fp16 MFMA, B-frags shared across caps ----
    stage(0, 0);
    for (int hs = 0; hs < 8; ++hs) {
        __syncthreads();
        if (hs < 7) stage(hs + 1, (hs + 1) & 1);
        const int b = hs & 1;
        #pragma unroll
        for (int ks = 0; ks < 2; ++ks) {
            half8 bf[4];
            #pragma unroll
            for (int j = 0; j < 4; ++j)
                bf[j] = *reinterpret_cast<const half8*>(wb + j * (16 * HD) + hs * 64 + ks * 32);
            #pragma unroll
            for (int cap = 0; cap < CPB; ++cap) {
                half8 af[4];
                #pragma unroll
                for (int i = 0; i < 4; ++i)
                    af[i] = *reinterpret_cast<const half8*>(&slab[b][cap][l15 + 16 * i][ks * 32 + l4 * 8]);
                #pragma unroll
                for (int i = 0; i < 4; ++i)
                    #pragma unroll
                    for (int j = 0; j < 4; ++j)
                        acc[cap][i * 4 + j] =
                            __builtin_amdgcn_mfma_f32_16x16x32_f16(af[i], bf[j], acc[cap][i * 4 + j], 0, 0, 0);
            }
        }
    }
    __syncthreads();

    // ---- routing: 3 iterations, x_hat register-resident ----
    for (int it = 0; it < 3; ++it) {
        if (it > 0) {
            if (wave < CPB) {                   // wave w handles capsule w softmax
                float v = bvec[wave][lane];
                float m = v;
                #pragma unroll
                for (int off = 32; off; off >>= 1) m = fmaxf(m, __shfl_xor(m, off));
                float e = expf(v - m);
                float s = e;
                #pragma unroll
                for (int off = 32; off; off >>= 1) s += __shfl_xor(s, off);
                dvec[wave][lane] = e / s;
            }
            __syncthreads();
        }

        // chat[g] for g = wave*64 + j*16 + l15, all in registers
        float chv[CPB][4];
        #pragma unroll
        for (int cap = 0; cap < CPB; ++cap) {
            #pragma unroll
            for (int j = 0; j < 4; ++j) chv[cap][j] = 0.f;
            #pragma unroll
            for (int i = 0; i < 4; ++i)
                #pragma unroll
                for (int r = 0; r < 4; ++r) {
                    float dk = (it == 0) ? (1.0f / 64.0f) : dvec[cap][i * 16 + l4 * 4 + r];
                    #pragma unroll
                    for (int j = 0; j < 4; ++j)
                        chv[cap][j] += dk * acc[cap][i * 4 + j][r];
                }
            #pragma unroll
            for (int j = 0; j < 4; ++j) {       // l4-reduce: sum the 4 k-chunks
                chv[cap][j] += __shfl_xor(chv[cap][j], 16);
                chv[cap][j] += __shfl_xor(chv[cap][j], 32);
            }
            if (l4 == 0) {
                #pragma unroll
                for (int j = 0; j < 4; ++j)
                    chatL[cap][wave * 64 + j * 16 + l15] = chv[cap][j];
            }
            float p = chv[cap][0] * chv[cap][0] + chv[cap][1] * chv[cap][1]
                    + chv[cap][2] * chv[cap][2] + chv[cap][3] * chv[cap][3];
            #pragma unroll
            for (int off = 1; off <= 8; off <<= 1) p += __shfl_xor(p, off);  // l15-reduce
            if (lane == 0) red[wave][cap] = p;
        }
        __syncthreads();
        if (tid == 0) {
            #pragma unroll
            for (int cap = 0; cap < CPB; ++cap) {
                float n2 = 0.f;
                #pragma unroll
                for (int w = 0; w < 8; ++w) n2 += red[w][cap];
                s_alpha[cap] = sqrtf(n2) / (1.0f + n2);
            }
        }
        __syncthreads();

        if (it < 2) {
            // b_k += alpha * sum_g xh[k][g] chat[g]
            #pragma unroll
            for (int cap = 0; cap < CPB; ++cap) {
                #pragma unroll
                for (int i = 0; i < 4; ++i)
                    #pragma unroll
                    for (int r = 0; r < 4; ++r) {
                        float s = acc[cap][i * 4 + 0][r] * chv[cap][0]
                                + acc[cap][i * 4 + 1][r] * chv[cap][1]
                                + acc[cap][i * 4 + 2][r] * chv[cap][2]
                                + acc[cap][i * 4 + 3][r] * chv[cap][3];
                        #pragma unroll
                        for (int off = 1; off <= 8; off <<= 1) s += __shfl_xor(s, off);  // l15-reduce
                        if (l15 == 0) bpart[wave][cap][i * 16 + l4 * 4 + r] = s;
                    }
            }
            __syncthreads();
            if (tid < CPB * KC) {
                int cap = tid >> 6, k = tid & 63;
                float t = 0.f;
                #pragma unroll
                for (int w = 0; w < 8; ++w) t += bpart[w][cap][k];
                bvec[cap][k] += s_alpha[cap] * t;
            }
            __syncthreads();
        } else {
            #pragma unroll
            for (int cap = 0; cap < CPB; ++cap)
                out[(size_t)(c0 + cap) * HD + tid] = s_alpha[cap] * chatL[cap][tid];
        }
    }
}

extern "C" void kernel_launch(void* const* d_in, const int* in_sizes, int n_in,
                              void* d_out, int out_size, void* d_ws, size_t ws_size,
                              hipStream_t stream) {
    const float* enc = (const float*)d_in[0];   // [1024, 64, 512] fp32
    const float* W   = (const float*)d_in[1];   // [512, 512] fp32
    float* out       = (float*)d_out;           // [1024, 512] fp32
    _Float16* W16    = (_Float16*)d_ws;         // 512 KB
    (void)in_sizes; (void)n_in; (void)ws_size; (void)out_size;

    cast_w_kernel<<<256, 256, 0, stream>>>(W, W16);
    routing_kernel<<<1024 / CPB, NT, 0, stream>>>(enc, W16, out);
}